// Round 1
// baseline (3575.210 us; speedup 1.0000x reference)
//
#include <hip/hip_runtime.h>
#include <stdint.h>

#define TSTEPS 256
#define BATCH  256
#define IDIM   512
#define HDIM   1024
#define KDIM   1536    // H + I
#define NSLOT  48      // KDIM/32
#define HSLOT  32      // HDIM/32

typedef short s16x8 __attribute__((ext_vector_type(8)));
typedef float f32x4 __attribute__((ext_vector_type(4)));
typedef unsigned long long u64;

// workspace layout (bytes)
#define WS_BUF0 0
#define WS_BUF1 (BATCH * HDIM * 2)            // 512 KB
#define WS_HF32 (BATCH * HDIM * 4)            // 1 MB   (after both bf16 bufs)
#define WS_CNT  (WS_HF32 + BATCH * HDIM * 4)  // 2 MB

__device__ __forceinline__ unsigned short f2bf(float f) {
    unsigned u = __builtin_bit_cast(unsigned, f);
    u += 0x7fffu + ((u >> 16) & 1u);   // round-to-nearest-even
    return (unsigned short)(u >> 16);
}

__global__ void zero_cnt_kernel(unsigned* c) { c[threadIdx.x] = 0u; }

__global__ __launch_bounds__(256, 1) void rclstm_kernel(
    const float* __restrict__ x, const float* __restrict__ Wg,
    const float* __restrict__ bgate, unsigned char* __restrict__ ws)
{
    const int tid  = threadIdx.x;
    const int lane = tid & 63;
    const int wv   = tid >> 6;           // wave 0..3
    const int hg   = blockIdx.x & 15;    // hidden group (64 cols)
    const int bg   = blockIdx.x >> 4;    // batch group  (16 rows)
    const int l16  = lane & 15;
    const int ksub = (lane >> 4) * 8;    // k sub-offset for A/B fragments
    const int row0 = (lane >> 4) * 4;    // C/D row base (m89-verified layout)

    __shared__ unsigned short comb[16][KDIM + 8];  // [h | x_t], padded rows
    __shared__ unsigned short hout[16][64];

    u64*      buf0 = (u64*)(ws + WS_BUF0);
    u64*      buf1 = (u64*)(ws + WS_BUF1);
    float*    hf32 = (float*)(ws + WS_HF32);
    unsigned* cnt  = (unsigned*)(ws + WS_CNT) + (unsigned)bg * 64u;

    const int jcol = hg * 64 + wv * 16 + l16;      // my hidden column

    // ---- W_gate fragments: load once, convert fp32->bf16, keep in VGPRs ----
    s16x8 wfrag[NSLOT];
    {
        const float* wrow = Wg + (size_t)jcol * KDIM + ksub;
#pragma unroll
        for (int s = 0; s < NSLOT; ++s) {
            float4 a = *(const float4*)(wrow + s * 32);
            float4 b = *(const float4*)(wrow + s * 32 + 4);
            s16x8 f;
            f[0] = (short)f2bf(a.x); f[1] = (short)f2bf(a.y);
            f[2] = (short)f2bf(a.z); f[3] = (short)f2bf(a.w);
            f[4] = (short)f2bf(b.x); f[5] = (short)f2bf(b.y);
            f[6] = (short)f2bf(b.z); f[7] = (short)f2bf(b.w);
            wfrag[s] = f;
        }
    }
    const float bj = bgate[jcol];

    f32x4 cst = {0.f, 0.f, 0.f, 0.f};   // cell state, stays in registers

#pragma unroll 1
    for (int t = 0; t < TSTEPS; ++t) {
        // ---- stage x[t] tile -> comb[:, 1024:1536] (plain loads, L2-cached) ----
        {
            const float* xs = x + (size_t)t * (BATCH * IDIM) + (size_t)bg * 16 * IDIM;
#pragma unroll
            for (int it = 0; it < 8; ++it) {
                int i = tid + it * 256;          // 0..2047
                int r = i >> 7, c4 = i & 127;
                float4 v = *(const float4*)(xs + r * IDIM + c4 * 4);
                u64 pk = (u64)f2bf(v.x) | ((u64)f2bf(v.y) << 16)
                       | ((u64)f2bf(v.z) << 32) | ((u64)f2bf(v.w) << 48);
                *(u64*)&comb[r][HDIM + c4 * 4] = pk;
            }
        }
        // ---- stage h[t] tile -> comb[:, 0:1024] (L2-bypass coherent loads) ----
        if (t > 0) {
            u64* hsrc = ((t & 1) ? buf1 : buf0) + (size_t)bg * 16 * 256;
#pragma unroll
            for (int it = 0; it < 16; ++it) {
                int i = tid + it * 256;          // 0..4095
                int r = i >> 8, ch = i & 255;
                u64 v = __hip_atomic_load(hsrc + r * 256 + ch,
                                          __ATOMIC_RELAXED, __HIP_MEMORY_SCOPE_AGENT);
                *(u64*)&comb[r][ch * 4] = v;
            }
        }
        __syncthreads();

        // ---- MFMA: pre = [h | x_t] @ W^T over K=1536, 4 interleaved accs ----
        f32x4 acc[4];
        {
            f32x4 z = {0.f, 0.f, 0.f, 0.f};
            acc[0] = z; acc[1] = z; acc[2] = z; acc[3] = z;
        }
        const unsigned short* arow = &comb[l16][ksub];
        if (t > 0) {
#pragma unroll
            for (int s = 0; s < HSLOT; ++s) {
                s16x8 a = *(const s16x8*)(arow + s * 32);
                acc[s & 3] = __builtin_amdgcn_mfma_f32_16x16x32_bf16(
                    a, wfrag[s], acc[s & 3], 0, 0, 0);
            }
        }
#pragma unroll
        for (int s = HSLOT; s < NSLOT; ++s) {
            s16x8 a = *(const s16x8*)(arow + s * 32);
            acc[s & 3] = __builtin_amdgcn_mfma_f32_16x16x32_bf16(
                a, wfrag[s], acc[s & 3], 0, 0, 0);
        }
        f32x4 pre4 = (acc[0] + acc[1]) + (acc[2] + acc[3]);

        // ---- elementwise gates (fp32) ----
        float hv[4];
#pragma unroll
        for (int r = 0; r < 4; ++r) {
            float pre = pre4[r] + bj;
            float g   = 1.0f / (1.0f + __expf(-pre));
            float tp  = 2.0f / (1.0f + __expf(-2.0f * pre)) - 1.0f;
            float cn  = g * (cst[r] + tp);
            cst[r] = cn;
            float tc  = 2.0f / (1.0f + __expf(-2.0f * cn)) - 1.0f;
            hv[r] = tc * g;
        }

        if (t == TSTEPS - 1) {
            // final h in fp32 for the output GEMM (kernel-end flush publishes it)
#pragma unroll
            for (int r = 0; r < 4; ++r)
                hf32[(size_t)(bg * 16 + row0 + r) * HDIM + jcol] = hv[r];
        } else {
            // pack h -> bf16 tile in LDS, then coherent 8B write-through stores
#pragma unroll
            for (int r = 0; r < 4; ++r)
                hout[row0 + r][wv * 16 + l16] = f2bf(hv[r]);
            __syncthreads();
            {
                u64* dst = ((t & 1) ? buf0 : buf1);
                int r = tid >> 4, ch = tid & 15;
                u64 v = *(const u64*)&hout[r][ch * 4];
                __hip_atomic_store(dst + (size_t)(bg * 16 + r) * 256 + hg * 16 + ch,
                                   v, __ATOMIC_RELAXED, __HIP_MEMORY_SCOPE_AGENT);
            }
            __syncthreads();   // drains all waves' stores before arrival
            if (tid == 0) {
                asm volatile("" ::: "memory");
                __hip_atomic_fetch_add(cnt, 1u, __ATOMIC_RELEASE,
                                       __HIP_MEMORY_SCOPE_AGENT);
                unsigned tgt = 16u * (unsigned)(t + 1);
                while (__hip_atomic_load(cnt, __ATOMIC_RELAXED,
                                         __HIP_MEMORY_SCOPE_AGENT) < tgt) {
                    __builtin_amdgcn_s_sleep(1);
                }
                asm volatile("" ::: "memory");
            }
            __syncthreads();
        }
    }
}

// out[b][i] = h_final[b][:] . W_out[i][:] + b_out[i]   (fp32)
__global__ __launch_bounds__(256) void out_kernel(
    const float* __restrict__ hf, const float* __restrict__ Wo,
    const float* __restrict__ bo, float* __restrict__ out)
{
    const int tid = threadIdx.x;
    const int col = (blockIdx.x & 15) * 32 + (tid & 31);
    const int r8  = tid >> 5;                 // 0..7
    const int b0  = (blockIdx.x >> 4) * 16;
    const float* wrow = Wo + (size_t)col * HDIM;
    const float* h0 = hf + (size_t)(b0 + r8) * HDIM;
    const float* h1 = hf + (size_t)(b0 + r8 + 8) * HDIM;
    float s0 = 0.f, s1 = 0.f;
#pragma unroll 4
    for (int k = 0; k < HDIM; k += 4) {
        float4 w = *(const float4*)(wrow + k);
        float4 a = *(const float4*)(h0 + k);
        float4 b = *(const float4*)(h1 + k);
        s0 += w.x * a.x + w.y * a.y + w.z * a.z + w.w * a.w;
        s1 += w.x * b.x + w.y * b.y + w.z * b.z + w.w * b.w;
    }
    out[(size_t)(b0 + r8) * IDIM + col]     = s0 + bo[col];
    out[(size_t)(b0 + r8 + 8) * IDIM + col] = s1 + bo[col];
}

extern "C" void kernel_launch(void* const* d_in, const int* in_sizes, int n_in,
                              void* d_out, int out_size, void* d_ws, size_t ws_size,
                              hipStream_t stream) {
    const float* x   = (const float*)d_in[0];
    const float* Wg  = (const float*)d_in[1];
    const float* bgt = (const float*)d_in[2];
    const float* Wo  = (const float*)d_in[3];
    const float* bo  = (const float*)d_in[4];
    unsigned char* ws = (unsigned char*)d_ws;

    zero_cnt_kernel<<<1, 1024, 0, stream>>>((unsigned*)(ws + WS_CNT));
    rclstm_kernel<<<256, 256, 0, stream>>>(x, Wg, bgt, ws);
    out_kernel<<<256, 256, 0, stream>>>((const float*)(ws + WS_HF32), Wo, bo,
                                        (float*)d_out);
}

// Round 2
// 2159.070 us; speedup vs baseline: 1.6559x; 1.6559x over previous
//
#include <hip/hip_runtime.h>
#include <stdint.h>

#define TSTEPS 256
#define BATCH  256
#define IDIM   512
#define HDIM   1024
#define KDIM   1536    // H + I
#define NSLOT  48      // KDIM/32
#define HSLOT  32      // HDIM/32

typedef short s16x8 __attribute__((ext_vector_type(8)));
typedef float f32x4 __attribute__((ext_vector_type(4)));
typedef unsigned long long u64;

// workspace layout (bytes)
#define WS_BUF0 0
#define WS_BUF1 (BATCH * HDIM * 2)            // 512 KB
#define WS_HF32 (BATCH * HDIM * 4)            // 1 MB
#define WS_CNT  (WS_HF32 + BATCH * HDIM * 4)  // 2 MB

__device__ __forceinline__ unsigned short f2bf(float f) {
    unsigned u = __builtin_bit_cast(unsigned, f);
    u += 0x7fffu + ((u >> 16) & 1u);   // round-to-nearest-even
    return (unsigned short)(u >> 16);
}

__global__ void zero_cnt_kernel(unsigned* c) { c[threadIdx.x] = 0u; }

__global__ __launch_bounds__(256, 1) void rclstm_kernel(
    const float* __restrict__ x, const float* __restrict__ Wg,
    const float* __restrict__ bgate, unsigned char* __restrict__ ws)
{
    const int tid  = threadIdx.x;
    const int lane = tid & 63;
    const int wv   = tid >> 6;           // wave 0..3
    const int hg   = blockIdx.x & 15;    // hidden group (64 cols)
    const int bg   = blockIdx.x >> 4;    // batch group  (16 rows)
    const int l16  = lane & 15;
    const int ksub = (lane >> 4) * 8;    // k sub-offset for A/B fragments
    const int row0 = (lane >> 4) * 4;    // C/D row base (m89-verified layout)

    __shared__ unsigned short comb[16][KDIM + 8];  // [h | x_t], padded rows

    unsigned short* buf0s = (unsigned short*)(ws + WS_BUF0);
    unsigned short* buf1s = (unsigned short*)(ws + WS_BUF1);
    float*    hf32 = (float*)(ws + WS_HF32);
    unsigned* cnt  = (unsigned*)(ws + WS_CNT) + (unsigned)bg * 64u;

    const int jcol = hg * 64 + wv * 16 + l16;      // my hidden column

    // ---- W_gate fragments: load once, convert fp32->bf16, keep in VGPRs ----
    s16x8 wfrag[NSLOT];
    {
        const float* wrow = Wg + (size_t)jcol * KDIM + ksub;
#pragma unroll
        for (int s = 0; s < NSLOT; ++s) {
            float4 a = *(const float4*)(wrow + s * 32);
            float4 b = *(const float4*)(wrow + s * 32 + 4);
            s16x8 f;
            f[0] = (short)f2bf(a.x); f[1] = (short)f2bf(a.y);
            f[2] = (short)f2bf(a.z); f[3] = (short)f2bf(a.w);
            f[4] = (short)f2bf(b.x); f[5] = (short)f2bf(b.y);
            f[6] = (short)f2bf(b.z); f[7] = (short)f2bf(b.w);
            wfrag[s] = f;
        }
    }
    const float bj = bgate[jcol];

    f32x4 cst = {0.f, 0.f, 0.f, 0.f};   // cell state, stays in registers

    // ---- prologue: prefetch x[0] tile into registers ----
    float4 xr[8];
    {
        const float* xs = x + (size_t)bg * 16 * IDIM;
#pragma unroll
        for (int it = 0; it < 8; ++it) {
            int i = tid + it * 256;
            int r = i >> 7, c4 = i & 127;
            xr[it] = *(const float4*)(xs + r * IDIM + c4 * 4);
        }
    }

#pragma unroll 1
    for (int t = 0; t < TSTEPS; ++t) {
        // ---- write prefetched x[t] -> comb[:, 1024:1536] ----
#pragma unroll
        for (int it = 0; it < 8; ++it) {
            int i = tid + it * 256;
            int r = i >> 7, c4 = i & 127;
            float4 v = xr[it];
            u64 pk = (u64)f2bf(v.x) | ((u64)f2bf(v.y) << 16)
                   | ((u64)f2bf(v.z) << 32) | ((u64)f2bf(v.w) << 48);
            *(u64*)&comb[r][HDIM + c4 * 4] = pk;
        }
        // ---- stage h[t] tile -> comb[:, 0:1024] (sc1 coherent loads) ----
        if (t > 0) {
            const u64* hsrc = (const u64*)((t & 1) ? buf1s : buf0s)
                              + (size_t)bg * 16 * 256;
#pragma unroll
            for (int it = 0; it < 16; ++it) {
                int i = tid + it * 256;
                int r = i >> 8, ch = i & 255;
                u64 v = __hip_atomic_load(hsrc + r * 256 + ch,
                                          __ATOMIC_RELAXED, __HIP_MEMORY_SCOPE_AGENT);
                *(u64*)&comb[r][ch * 4] = v;
            }
        }
        __syncthreads();

        // ---- MFMA: pre = [h | x_t] @ W^T over K=1536, 4 interleaved accs ----
        f32x4 acc[4];
        {
            f32x4 z = {0.f, 0.f, 0.f, 0.f};
            acc[0] = z; acc[1] = z; acc[2] = z; acc[3] = z;
        }
        const unsigned short* arow = &comb[l16][ksub];
        if (t > 0) {
#pragma unroll
            for (int s = 0; s < HSLOT; ++s) {
                s16x8 a = *(const s16x8*)(arow + s * 32);
                acc[s & 3] = __builtin_amdgcn_mfma_f32_16x16x32_bf16(
                    a, wfrag[s], acc[s & 3], 0, 0, 0);
            }
        }
#pragma unroll
        for (int s = HSLOT; s < NSLOT; ++s) {
            s16x8 a = *(const s16x8*)(arow + s * 32);
            acc[s & 3] = __builtin_amdgcn_mfma_f32_16x16x32_bf16(
                a, wfrag[s], acc[s & 3], 0, 0, 0);
        }
        f32x4 pre4 = (acc[0] + acc[1]) + (acc[2] + acc[3]);

        // ---- elementwise gates (fp32) ----
        float hv[4];
#pragma unroll
        for (int r = 0; r < 4; ++r) {
            float pre = pre4[r] + bj;
            float g   = 1.0f / (1.0f + __expf(-pre));
            float tp  = 2.0f / (1.0f + __expf(-2.0f * pre)) - 1.0f;
            float cn  = g * (cst[r] + tp);
            cst[r] = cn;
            float tc  = 2.0f / (1.0f + __expf(-2.0f * cn)) - 1.0f;
            hv[r] = tc * g;
        }

        if (t == TSTEPS - 1) {
            // final h in fp32 for the output GEMM (kernel-end flush publishes it)
#pragma unroll
            for (int r = 0; r < 4; ++r)
                hf32[(size_t)(bg * 16 + row0 + r) * HDIM + jcol] = hv[r];
        } else {
            // direct bf16 write-through stores (sc1), 4 x 2B per lane
            unsigned short* dst = (t & 1) ? buf0s : buf1s;
#pragma unroll
            for (int r = 0; r < 4; ++r)
                __hip_atomic_store(dst + (size_t)(bg * 16 + row0 + r) * HDIM + jcol,
                                   f2bf(hv[r]),
                                   __ATOMIC_RELAXED, __HIP_MEMORY_SCOPE_AGENT);
            // drain all waves' stores (syncthreads emits vmcnt(0) per wave)
            // and ensure all waves are done reading comb before next overwrite
            __syncthreads();

            // prefetch x[t+1] into registers; latency hides under the poll
            {
                const float* xs = x + (size_t)(t + 1) * (BATCH * IDIM)
                                    + (size_t)bg * 16 * IDIM;
#pragma unroll
                for (int it = 0; it < 8; ++it) {
                    int i = tid + it * 256;
                    int r = i >> 7, c4 = i & 127;
                    xr[it] = *(const float4*)(xs + r * IDIM + c4 * 4);
                }
            }

            // relaxed arrival: stores already at coherence point (sc1 + syncthreads)
            if (tid == 0) {
                asm volatile("" ::: "memory");
                __hip_atomic_fetch_add(cnt, 1u, __ATOMIC_RELAXED,
                                       __HIP_MEMORY_SCOPE_AGENT);
                unsigned tgt = 16u * (unsigned)(t + 1);
                while (__hip_atomic_load(cnt, __ATOMIC_RELAXED,
                                         __HIP_MEMORY_SCOPE_AGENT) < tgt) { }
                asm volatile("" ::: "memory");
            }
            __syncthreads();
        }
    }
}

// out[b][i] = h_final[b][:] . W_out[i][:] + b_out[i]   (fp32)
__global__ __launch_bounds__(256) void out_kernel(
    const float* __restrict__ hf, const float* __restrict__ Wo,
    const float* __restrict__ bo, float* __restrict__ out)
{
    const int tid = threadIdx.x;
    const int col = (blockIdx.x & 15) * 32 + (tid & 31);
    const int r8  = tid >> 5;                 // 0..7
    const int b0  = (blockIdx.x >> 4) * 16;
    const float* wrow = Wo + (size_t)col * HDIM;
    const float* h0 = hf + (size_t)(b0 + r8) * HDIM;
    const float* h1 = hf + (size_t)(b0 + r8 + 8) * HDIM;
    float s0 = 0.f, s1 = 0.f;
#pragma unroll 4
    for (int k = 0; k < HDIM; k += 4) {
        float4 w = *(const float4*)(wrow + k);
        float4 a = *(const float4*)(h0 + k);
        float4 b = *(const float4*)(h1 + k);
        s0 += w.x * a.x + w.y * a.y + w.z * a.z + w.w * a.w;
        s1 += w.x * b.x + w.y * b.y + w.z * b.z + w.w * b.w;
    }
    out[(size_t)(b0 + r8) * IDIM + col]     = s0 + bo[col];
    out[(size_t)(b0 + r8 + 8) * IDIM + col] = s1 + bo[col];
}

extern "C" void kernel_launch(void* const* d_in, const int* in_sizes, int n_in,
                              void* d_out, int out_size, void* d_ws, size_t ws_size,
                              hipStream_t stream) {
    const float* x   = (const float*)d_in[0];
    const float* Wg  = (const float*)d_in[1];
    const float* bgt = (const float*)d_in[2];
    const float* Wo  = (const float*)d_in[3];
    const float* bo  = (const float*)d_in[4];
    unsigned char* ws = (unsigned char*)d_ws;

    zero_cnt_kernel<<<1, 1024, 0, stream>>>((unsigned*)(ws + WS_CNT));
    rclstm_kernel<<<256, 256, 0, stream>>>(x, Wg, bgt, ws);
    out_kernel<<<256, 256, 0, stream>>>((const float*)(ws + WS_HF32), Wo, bo,
                                        (float*)d_out);
}

// Round 3
// 2066.301 us; speedup vs baseline: 1.7302x; 1.0449x over previous
//
#include <hip/hip_runtime.h>
#include <stdint.h>

#define TSTEPS 256
#define BATCH  256
#define IDIM   512
#define HDIM   1024
#define KDIM   1536    // H + I
#define NSLOT  48      // KDIM/32
#define HSLOT  32      // HDIM/32
#define XSLOT  16      // IDIM/32

typedef short s16x8 __attribute__((ext_vector_type(8)));
typedef float f32x4 __attribute__((ext_vector_type(4)));
typedef unsigned long long u64;

// workspace layout (bytes)
#define WS_BUF0 0
#define WS_BUF1 (BATCH * HDIM * 2)            // 512 KB
#define WS_HF32 (BATCH * HDIM * 4)            // 1 MB
#define WS_CNT  (WS_HF32 + BATCH * HDIM * 4)  // 2 MB   : 16 groups x 64 u32
#define WS_MEMB (WS_CNT  + 4096)              // 256 u32 : member XCD per (bg,hg)
#define WS_ROST (WS_MEMB + 1024)              // 8 u32   : per-XCD roster
#define WS_GBAR (WS_ROST + 64)                // 1 u32   : grid barrier
#define WS_CFLG (WS_GBAR + 64)                // 256 u32 : position claim flags
#define WS_ZEND (WS_CFLG + 1024)

__device__ __forceinline__ unsigned short f2bf(float f) {
    unsigned u = __builtin_bit_cast(unsigned, f);
    u += 0x7fffu + ((u >> 16) & 1u);   // round-to-nearest-even
    return (unsigned short)(u >> 16);
}

__global__ void zero_cnt_kernel(unsigned* c) {
    // clears WS_CNT .. WS_ZEND (cnt, memb, roster, gbar, cflag)
    int n = (WS_ZEND - WS_CNT) / 4;
    for (int i = threadIdx.x; i < n; i += blockDim.x) c[i] = 0u;
}

__global__ __launch_bounds__(256, 1) void rclstm_kernel(
    const float* __restrict__ x, const float* __restrict__ Wg,
    const float* __restrict__ bgate, unsigned char* __restrict__ ws)
{
    const int tid  = threadIdx.x;
    const int lane = tid & 63;
    const int wv   = tid >> 6;           // wave 0..3
    const int l16  = lane & 15;
    const int ksub = (lane >> 4) * 8;    // k sub-offset for A/B fragments
    const int row0 = (lane >> 4) * 4;    // C/D row base (m89-verified layout)

    __shared__ unsigned short comb[16][HDIM + 8];  // h tile only (x is reg-direct)
    __shared__ int shmeta[2];                      // [0]=pos, [1]=pure

    unsigned short* buf0s  = (unsigned short*)(ws + WS_BUF0);
    unsigned short* buf1s  = (unsigned short*)(ws + WS_BUF1);
    float*          hf32   = (float*)(ws + WS_HF32);
    unsigned*       cntb   = (unsigned*)(ws + WS_CNT);
    unsigned*       memb   = (unsigned*)(ws + WS_MEMB);
    unsigned*       roster = (unsigned*)(ws + WS_ROST);
    unsigned*       gbar   = (unsigned*)(ws + WS_GBAR);
    unsigned*       cflag  = (unsigned*)(ws + WS_CFLG);

    unsigned xcd;
    asm volatile("s_getreg_b32 %0, hwreg(HW_REG_XCC_ID)" : "=s"(xcd));

    // ---- roster claim: bind this block to a (bg,hg) slot on ITS OWN XCD ----
    if (tid == 0) {
        int pos;
        unsigned slot = __hip_atomic_fetch_add(roster + xcd, 1u,
                                               __ATOMIC_RELAXED, __HIP_MEMORY_SCOPE_AGENT);
        if (slot < 32u) {
            pos = (int)(xcd * 32u + slot);          // bg = pos>>4 in {2*xcd, 2*xcd+1}
            __hip_atomic_store(cflag + pos, 1u,
                               __ATOMIC_RELAXED, __HIP_MEMORY_SCOPE_AGENT);
            asm volatile("s_waitcnt vmcnt(0)" ::: "memory");
            __hip_atomic_fetch_add(gbar, 1u, __ATOMIC_RELAXED, __HIP_MEMORY_SCOPE_AGENT);
        } else {
            // scheduler gave this XCD >32 blocks: claim any leftover position
            __hip_atomic_fetch_add(gbar, 1u, __ATOMIC_RELAXED, __HIP_MEMORY_SCOPE_AGENT);
            while (__hip_atomic_load(gbar, __ATOMIC_RELAXED,
                                     __HIP_MEMORY_SCOPE_AGENT) < 256u) {}
            pos = -1;
            for (int p2 = 0; pos < 0; p2 = (p2 + 1) & 255) {
                unsigned old = __hip_atomic_fetch_add(cflag + p2, 1u,
                                   __ATOMIC_RELAXED, __HIP_MEMORY_SCOPE_AGENT);
                if (old == 0u) pos = p2;
            }
        }
        shmeta[0] = pos;
    }
    __syncthreads();
    const int pos = shmeta[0];
    const int bg  = pos >> 4;            // batch group  (16 rows)
    const int hg  = pos & 15;            // hidden group (64 cols)
    unsigned* cnt = cntb + bg * 64;

    // ---- group membership: pure <=> all 16 members on one XCD ----
    if (wv == 0) {
        if (lane == 0) {
            __hip_atomic_store(memb + pos, xcd,
                               __ATOMIC_RELAXED, __HIP_MEMORY_SCOPE_AGENT);
            asm volatile("s_waitcnt vmcnt(0)" ::: "memory");
            __hip_atomic_fetch_add(cnt, 1u, __ATOMIC_RELAXED, __HIP_MEMORY_SCOPE_AGENT);
            while (__hip_atomic_load(cnt, __ATOMIC_RELAXED,
                                     __HIP_MEMORY_SCOPE_AGENT) < 16u) {}
        }
        unsigned e = (lane < 16)
            ? __hip_atomic_load(memb + bg * 16 + lane,
                                __ATOMIC_RELAXED, __HIP_MEMORY_SCOPE_AGENT)
            : xcd;
        int allok = __all(e == xcd);
        if (lane == 0) shmeta[1] = allok;
    }
    __syncthreads();
    const bool pure = shmeta[1] != 0;

    const int jcol = hg * 64 + wv * 16 + l16;      // my hidden column

    // ---- W_gate fragments: load once, fp32->bf16, keep in VGPRs (192) ----
    s16x8 wfrag[NSLOT];
    {
        const float* wrow = Wg + (size_t)jcol * KDIM + ksub;
#pragma unroll
        for (int s = 0; s < NSLOT; ++s) {
            float4 a = *(const float4*)(wrow + s * 32);
            float4 b = *(const float4*)(wrow + s * 32 + 4);
            s16x8 f;
            f[0] = (short)f2bf(a.x); f[1] = (short)f2bf(a.y);
            f[2] = (short)f2bf(a.z); f[3] = (short)f2bf(a.w);
            f[4] = (short)f2bf(b.x); f[5] = (short)f2bf(b.y);
            f[6] = (short)f2bf(b.z); f[7] = (short)f2bf(b.w);
            wfrag[s] = f;
        }
    }
    const float bj = bgate[jcol];

    // x A-fragments straight from global fp32 (no LDS pass)
    s16x8 xfrag[XSLOT];
    auto loadx = [&](int tt) {
        const float* xr_ = x + (size_t)tt * (BATCH * IDIM)
                             + (size_t)(bg * 16 + l16) * IDIM + ksub;
#pragma unroll
        for (int si = 0; si < XSLOT; ++si) {
            float4 a = *(const float4*)(xr_ + si * 32);
            float4 b = *(const float4*)(xr_ + si * 32 + 4);
            s16x8 f;
            f[0] = (short)f2bf(a.x); f[1] = (short)f2bf(a.y);
            f[2] = (short)f2bf(a.z); f[3] = (short)f2bf(a.w);
            f[4] = (short)f2bf(b.x); f[5] = (short)f2bf(b.y);
            f[6] = (short)f2bf(b.z); f[7] = (short)f2bf(b.w);
            xfrag[si] = f;
        }
    };
    loadx(0);

    f32x4 cst = {0.f, 0.f, 0.f, 0.f};   // cell state, stays in registers

#pragma unroll 1
    for (int t = 0; t < TSTEPS; ++t) {
        // ---- stage h[t] tile -> comb (pure: sc0/L2; impure: sc1/L3) ----
        if (t > 0) {
            const u64* hsrc = (const u64*)((t & 1) ? buf1s : buf0s)
                              + (size_t)bg * 16 * 256;
            u64 hv16[16];
            if (pure) {
#pragma unroll
                for (int it = 0; it < 16; ++it) {
                    int i = tid + it * 256;
                    const u64* p = hsrc + (i >> 8) * 256 + (i & 255);
                    asm volatile("global_load_dwordx2 %0, %1, off sc0"
                                 : "=&v"(hv16[it]) : "v"(p) : "memory");
                }
                asm volatile("s_waitcnt vmcnt(0)" ::: "memory");
                __builtin_amdgcn_sched_barrier(0);
            } else {
#pragma unroll
                for (int it = 0; it < 16; ++it) {
                    int i = tid + it * 256;
                    hv16[it] = __hip_atomic_load(hsrc + (i >> 8) * 256 + (i & 255),
                                                 __ATOMIC_RELAXED, __HIP_MEMORY_SCOPE_AGENT);
                }
            }
#pragma unroll
            for (int it = 0; it < 16; ++it) {
                int i = tid + it * 256;
                *(u64*)&comb[i >> 8][(i & 255) * 4] = hv16[it];
            }
        }
        __syncthreads();

        // ---- MFMA: h slots from LDS, x slots from registers ----
        f32x4 acc[4];
        {
            f32x4 z = {0.f, 0.f, 0.f, 0.f};
            acc[0] = z; acc[1] = z; acc[2] = z; acc[3] = z;
        }
        const unsigned short* arow = &comb[l16][ksub];
        if (t > 0) {
#pragma unroll
            for (int s = 0; s < HSLOT; ++s) {
                s16x8 a = *(const s16x8*)(arow + s * 32);
                acc[s & 3] = __builtin_amdgcn_mfma_f32_16x16x32_bf16(
                    a, wfrag[s], acc[s & 3], 0, 0, 0);
            }
        }
#pragma unroll
        for (int si = 0; si < XSLOT; ++si) {
            acc[si & 3] = __builtin_amdgcn_mfma_f32_16x16x32_bf16(
                xfrag[si], wfrag[HSLOT + si], acc[si & 3], 0, 0, 0);
        }
        f32x4 pre4 = (acc[0] + acc[1]) + (acc[2] + acc[3]);

        // ---- elementwise gates (fp32) ----
        float ho[4];
#pragma unroll
        for (int r = 0; r < 4; ++r) {
            float pre = pre4[r] + bj;
            float g   = 1.0f / (1.0f + __expf(-pre));
            float tp  = 2.0f / (1.0f + __expf(-2.0f * pre)) - 1.0f;
            float cn  = g * (cst[r] + tp);
            cst[r] = cn;
            float tc  = 2.0f / (1.0f + __expf(-2.0f * cn)) - 1.0f;
            ho[r] = tc * g;
        }

        if (t == TSTEPS - 1) {
#pragma unroll
            for (int r = 0; r < 4; ++r)
                hf32[(size_t)(bg * 16 + row0 + r) * HDIM + jcol] = ho[r];
        } else {
            unsigned short* dst = (t & 1) ? buf0s : buf1s;
            if (pure) {
#pragma unroll
                for (int r = 0; r < 4; ++r)
                    dst[(size_t)(bg * 16 + row0 + r) * HDIM + jcol] = f2bf(ho[r]);
            } else {
#pragma unroll
                for (int r = 0; r < 4; ++r)
                    __hip_atomic_store(dst + (size_t)(bg * 16 + row0 + r) * HDIM + jcol,
                                       f2bf(ho[r]),
                                       __ATOMIC_RELAXED, __HIP_MEMORY_SCOPE_AGENT);
            }
            __syncthreads();   // drains stores (vmcnt 0) + comb reads done

            // arrival (issue ASAP, before the x-prefetch pack work)
            if (tid == 0) {
                if (pure) {
                    unsigned one = 1u;
                    asm volatile("global_atomic_add %0, %1, off"
                                 :: "v"(cnt), "v"(one) : "memory");
                } else {
                    __hip_atomic_fetch_add(cnt, 1u, __ATOMIC_RELAXED,
                                           __HIP_MEMORY_SCOPE_AGENT);
                }
            }

            // prefetch + pack x[t+1]; latency hides under peers' arrivals/poll
            loadx(t + 1);

            if (tid == 0) {
                unsigned tgt = 16u * (unsigned)(t + 2);   // +16 from init barrier
                if (pure) {
                    unsigned v;
                    do {
                        asm volatile("global_load_dword %0, %1, off sc0\n\t"
                                     "s_waitcnt vmcnt(0)"
                                     : "=&v"(v) : "v"(cnt) : "memory");
                    } while (v < tgt);
                } else {
                    while (__hip_atomic_load(cnt, __ATOMIC_RELAXED,
                                             __HIP_MEMORY_SCOPE_AGENT) < tgt) {}
                }
            }
            __syncthreads();
        }
    }
}

// out[b][i] = h_final[b][:] . W_out[i][:] + b_out[i]   (fp32), h staged in LDS
__global__ __launch_bounds__(256) void out_kernel(
    const float* __restrict__ hf, const float* __restrict__ Wo,
    const float* __restrict__ bo, float* __restrict__ out)
{
    __shared__ float hs[16][HDIM];   // 64 KB
    const int tid = threadIdx.x;
    const int cb  = blockIdx.x & 15;
    const int b0  = (blockIdx.x >> 4) * 16;
#pragma unroll
    for (int it = 0; it < 16; ++it) {
        int i = tid + it * 256;
        int r = i >> 8, c = i & 255;
        *(float4*)&hs[r][c * 4] = *(const float4*)(hf + (size_t)(b0 + r) * HDIM + c * 4);
    }
    __syncthreads();
    const int col = cb * 32 + (tid & 31);
    const int r0  = (tid >> 5) * 2;
    const float* wrow = Wo + (size_t)col * HDIM;
    float s0 = 0.f, s1 = 0.f;
#pragma unroll 8
    for (int k = 0; k < HDIM; k += 4) {
        float4 w = *(const float4*)(wrow + k);
        float4 a = *(const float4*)&hs[r0][k];
        float4 b = *(const float4*)&hs[r0 + 1][k];
        s0 += w.x * a.x + w.y * a.y + w.z * a.z + w.w * a.w;
        s1 += w.x * b.x + w.y * b.y + w.z * b.z + w.w * b.w;
    }
    out[(size_t)(b0 + r0) * IDIM + col]     = s0 + bo[col];
    out[(size_t)(b0 + r0 + 1) * IDIM + col] = s1 + bo[col];
}

extern "C" void kernel_launch(void* const* d_in, const int* in_sizes, int n_in,
                              void* d_out, int out_size, void* d_ws, size_t ws_size,
                              hipStream_t stream) {
    const float* x   = (const float*)d_in[0];
    const float* Wg  = (const float*)d_in[1];
    const float* bgt = (const float*)d_in[2];
    const float* Wo  = (const float*)d_in[3];
    const float* bo  = (const float*)d_in[4];
    unsigned char* ws = (unsigned char*)d_ws;

    zero_cnt_kernel<<<1, 1024, 0, stream>>>((unsigned*)(ws + WS_CNT));
    rclstm_kernel<<<256, 256, 0, stream>>>(x, Wg, bgt, ws);
    out_kernel<<<256, 256, 0, stream>>>((const float*)(ws + WS_HF32), Wo, bo,
                                        (float*)d_out);
}